// Round 1
// baseline (431.458 us; speedup 1.0000x reference)
//
#include <hip/hip_runtime.h>

// Haar DWT level-1 on (8,32,512,512) f32 -> 4 x (8,32,256,256) f32 (LL,LH,HL,HH concat).
// Memory-bound: 256 MiB in + 256 MiB out. Each thread: 4 output pixels,
// 4x float4 coalesced loads (two input rows), 4x float4 coalesced stores.

__global__ __launch_bounds__(256) void haar_dwt_kernel(const float* __restrict__ x,
                                                       float* __restrict__ out,
                                                       int nquads) {
    int t = blockIdx.x * blockDim.x + threadIdx.x;
    if (t >= nquads) return;

    // Output plane is 256x256; each thread covers 4 consecutive output cols.
    const int QPR = 64;          // quads per output row (256/4)
    const int QPP = 256 * QPR;   // quads per plane
    int n   = t / QPP;
    int rem = t - n * QPP;
    int oy  = rem / QPR;
    int qc  = rem - oy * QPR;
    int ox  = qc * 4;            // first output col of this quad

    // Input rows 2*oy and 2*oy+1, cols [2*ox, 2*ox+8)
    const size_t plane_in = 512 * 512;
    const float* rowt = x + (size_t)n * plane_in + (size_t)(2 * oy) * 512 + 2 * ox;
    const float* rowb = rowt + 512;

    float4 t0 = reinterpret_cast<const float4*>(rowt)[0];
    float4 t1 = reinterpret_cast<const float4*>(rowt)[1];
    float4 b0 = reinterpret_cast<const float4*>(rowb)[0];
    float4 b1 = reinterpret_cast<const float4*>(rowb)[1];

    // a = even-row even-col, b = even-row odd-col, c = odd-row even-col, d = odd-row odd-col
    float a[4] = {t0.x, t0.z, t1.x, t1.z};
    float b[4] = {t0.y, t0.w, t1.y, t1.w};
    float c[4] = {b0.x, b0.z, b1.x, b1.z};
    float d[4] = {b0.y, b0.w, b1.y, b1.w};

    float4 ll, lh, hl, hh;
    float* pll = reinterpret_cast<float*>(&ll);
    float* plh = reinterpret_cast<float*>(&lh);
    float* phl = reinterpret_cast<float*>(&hl);
    float* phh = reinterpret_cast<float*>(&hh);

#pragma unroll
    for (int i = 0; i < 4; ++i) {
        const float q = 0.25f;
        pll[i] = q * ( a[i] + b[i] + c[i] + d[i]);
        plh[i] = q * (-a[i] - b[i] + c[i] + d[i]);
        phl[i] = q * (-a[i] + b[i] - c[i] + d[i]);
        phh[i] = q * ( a[i] - b[i] - c[i] + d[i]);
    }

    const size_t sub = (size_t)8 * 32 * 256 * 256;   // elements per subband
    size_t oidx = (size_t)n * (256 * 256) + (size_t)oy * 256 + ox;

    reinterpret_cast<float4*>(out + oidx)[0]           = ll;
    reinterpret_cast<float4*>(out + sub + oidx)[0]     = lh;
    reinterpret_cast<float4*>(out + 2 * sub + oidx)[0] = hl;
    reinterpret_cast<float4*>(out + 3 * sub + oidx)[0] = hh;
}

extern "C" void kernel_launch(void* const* d_in, const int* in_sizes, int n_in,
                              void* d_out, int out_size, void* d_ws, size_t ws_size,
                              hipStream_t stream) {
    const float* x = (const float*)d_in[0];
    float* out = (float*)d_out;

    const int nquads = 8 * 32 * 256 * 64;  // 4,194,304 threads, 4 px each
    const int block = 256;
    const int grid = nquads / block;       // 16384, exact

    haar_dwt_kernel<<<grid, block, 0, stream>>>(x, out, nquads);
}